// Round 3
// baseline (196.019 us; speedup 1.0000x reference)
//
#include <hip/hip_runtime.h>
#include <math.h>

#define EPS 1e-5f
#define B_ 8
#define C_ 512
#define S_ 2048
#define IC_ 64
#define IS_ 256
#define DS_ 32

// ws layout (float offsets)
#define OFF_CONST 0
#define OFF_THT   1024                       // thetaT [S_][512]: [t][b*64+c]
#define OFF_PHT   (OFF_THT + S_*C_)          // phiT   [S_][512]
#define OFF_A     (OFF_PHT + S_*C_)          // A [2][256][512]
#define OFF_G     (OFF_A + 2*IS_*C_)         // g [8][256][2048]
#define OFF_AP    OFF_G                      // partials [8][2][256][512] (aliased; dead before k3)
#define OFF_GATE  (OFF_G + B_*IS_*S_)        // gate [8][2048]

// ---------------------------------------------------------------- k0: fold BN
__global__ __launch_bounds__(256) void k0_consts(
    const float* tg, const float* tb, const float* tm, const float* tv,
    const float* pg, const float* pb, const float* pm, const float* pv,
    const float* gg, const float* gb, const float* gm, const float* gv,
    const float* w1g, const float* w1b, const float* w1m, const float* w1v,
    const float* w2g, const float* w2b, const float* w2m, const float* w2v,
    float* cst) {
  int i = threadIdx.x;
  if (i < 64) {
    float a = tg[i] * rsqrtf(tv[i] + EPS);
    cst[i] = a; cst[64 + i] = tb[i] - tm[i] * a;
    float ap = pg[i] * rsqrtf(pv[i] + EPS);
    cst[128 + i] = ap; cst[192 + i] = pb[i] - pm[i] * ap;
  }
  if (i < 256) {
    float a = gg[i] * rsqrtf(gv[i] + EPS);
    cst[256 + i] = a; cst[512 + i] = gb[i] - gm[i] * a;
  }
  if (i < 32) {
    float a = w1g[i] * rsqrtf(w1v[i] + EPS);
    cst[768 + i] = a; cst[800 + i] = w1b[i] - w1m[i] * a;
  }
  if (i == 0) {
    float a = w2g[0] * rsqrtf(w2v[0] + EPS);
    cst[832] = a; cst[833] = w2b[0] - w2m[0] * a;
  }
}

// ------------------------------------------- k1: theta/phi = relu(bn(W @ x))
// grid (32 s-tiles, 8 b, 2 mats), 512 threads. 4x2 tile, T14 staged, 8 chunks.
__global__ __launch_bounds__(512) void k1_theta_phi(
    const float* __restrict__ x, const float* __restrict__ Wt,
    const float* __restrict__ Wp, const float* __restrict__ cst,
    float* __restrict__ thetaT, float* __restrict__ phiT) {
  __shared__ float lw[64 * 68];   // [m][k] pad 68
  __shared__ float lx[64 * 66];   // [k][s] pad 66
  const int tid = threadIdx.x;
  const int s0  = blockIdx.x * 64;
  const int b   = blockIdx.y;
  const int mt  = blockIdx.z;
  const float* Wsrc = mt ? Wp : Wt;
  const float* xb   = x + (size_t)b * C_ * S_;
  const int r0 = tid >> 4;        // 0..31 staging row
  const int c0 = tid & 15;        // staging col quad
  const int tmg = tid >> 5;       // 0..15 -> 4 m-rows
  const int tsg = tid & 31;       // 0..31 -> 2 s-cols
  float4 wreg[2], xreg[2];
  float acc[4][2] = {};

#define K1_LOAD(KC) do {                                                      \
    _Pragma("unroll")                                                         \
    for (int p = 0; p < 2; ++p) {                                             \
      int row = r0 + 32 * p;                                                  \
      wreg[p] = *(const float4*)&Wsrc[(size_t)row * C_ + (KC) + c0 * 4];      \
      xreg[p] = *(const float4*)&xb[(size_t)((KC) + row) * S_ + s0 + c0 * 4]; \
    } } while (0)

  K1_LOAD(0);
  for (int c = 0; c < 8; ++c) {
    if (c) __syncthreads();
#pragma unroll
    for (int p = 0; p < 2; ++p) {
      int row = r0 + 32 * p;
      *(float4*)&lw[row * 68 + c0 * 4] = wreg[p];
      *(float4*)&lx[row * 66 + c0 * 4] = xreg[p];
    }
    __syncthreads();
    if (c < 7) K1_LOAD((c + 1) * 64);
#pragma unroll 4
    for (int k4 = 0; k4 < 16; ++k4) {
      float4 av[4]; float2 bv[4];
#pragma unroll
      for (int i = 0; i < 4; ++i)
        av[i] = *(const float4*)&lw[(tmg * 4 + i) * 68 + k4 * 4];
#pragma unroll
      for (int kk = 0; kk < 4; ++kk)
        bv[kk] = *(const float2*)&lx[(k4 * 4 + kk) * 66 + tsg * 2];
#pragma unroll
      for (int i = 0; i < 4; ++i) {
        acc[i][0] += av[i].x * bv[0].x + av[i].y * bv[1].x +
                     av[i].z * bv[2].x + av[i].w * bv[3].x;
        acc[i][1] += av[i].x * bv[0].y + av[i].y * bv[1].y +
                     av[i].z * bv[2].y + av[i].w * bv[3].y;
      }
    }
  }
#undef K1_LOAD
  const float* ac = cst + mt * 128;
  float* outT = mt ? phiT : thetaT;
#pragma unroll
  for (int j = 0; j < 2; ++j) {
    float4 q;
#pragma unroll
    for (int i = 0; i < 4; ++i) {
      int m = tmg * 4 + i;
      float v = ac[m] * acc[i][j] + ac[64 + m];
      ((float*)&q)[i] = v > 0.f ? v : 0.f;
    }
    *(float4*)&outT[(size_t)(s0 + tsg * 2 + j) * C_ + b * IC_ + tmg * 4] = q;
  }
}

// -------- k2: A[mat] = Wgg[:, mat*S:(mat+1)*S] @ (mat? thetaT : phiT)
// grid (8 n, 4 o, mat*8+part), 512 threads. split-K 8 (K=256), 4 chunks.
__global__ __launch_bounds__(512) void k2_factor(
    const float* __restrict__ Wgg, const float* __restrict__ ws,
    float* __restrict__ Ap) {
  __shared__ float lw[64 * 68];   // [o][t] pad 68
  __shared__ float lx[64 * 66];   // [t][n] pad 66
  const int tid  = threadIdx.x;
  const int n0   = blockIdx.x * 64;
  const int o0   = blockIdx.y * 64;
  const int mat  = blockIdx.z >> 3;
  const int part = blockIdx.z & 7;
  const float* Bm = ws + (mat ? OFF_THT : OFF_PHT);
  const int t0 = part * 256;
  const int r0 = tid >> 4;
  const int c0 = tid & 15;
  const int tmg = tid >> 5;
  const int tsg = tid & 31;
  float4 wreg[2], xreg[2];
  float acc[4][2] = {};

#define K2_LOAD(KC) do {                                                      \
    _Pragma("unroll")                                                         \
    for (int p = 0; p < 2; ++p) {                                             \
      int row = r0 + 32 * p;                                                  \
      wreg[p] = *(const float4*)&Wgg[(size_t)(o0 + row) * (2 * S_) +          \
                                     mat * S_ + t0 + (KC) + c0 * 4];          \
      xreg[p] = *(const float4*)&Bm[(size_t)(t0 + (KC) + row) * C_ +          \
                                    n0 + c0 * 4];                             \
    } } while (0)

  K2_LOAD(0);
  for (int c = 0; c < 4; ++c) {
    if (c) __syncthreads();
#pragma unroll
    for (int p = 0; p < 2; ++p) {
      int row = r0 + 32 * p;
      *(float4*)&lw[row * 68 + c0 * 4] = wreg[p];
      *(float4*)&lx[row * 66 + c0 * 4] = xreg[p];
    }
    __syncthreads();
    if (c < 3) K2_LOAD((c + 1) * 64);
#pragma unroll 4
    for (int k4 = 0; k4 < 16; ++k4) {
      float4 av[4]; float2 bv[4];
#pragma unroll
      for (int i = 0; i < 4; ++i)
        av[i] = *(const float4*)&lw[(tmg * 4 + i) * 68 + k4 * 4];
#pragma unroll
      for (int kk = 0; kk < 4; ++kk)
        bv[kk] = *(const float2*)&lx[(k4 * 4 + kk) * 66 + tsg * 2];
#pragma unroll
      for (int i = 0; i < 4; ++i) {
        acc[i][0] += av[i].x * bv[0].x + av[i].y * bv[1].x +
                     av[i].z * bv[2].x + av[i].w * bv[3].x;
        acc[i][1] += av[i].x * bv[0].y + av[i].y * bv[1].y +
                     av[i].z * bv[2].y + av[i].w * bv[3].y;
      }
    }
  }
#undef K2_LOAD
#pragma unroll
  for (int i = 0; i < 4; ++i) {
    float2 q = make_float2(acc[i][0], acc[i][1]);
    *(float2*)&Ap[((size_t)(part * 2 + mat) * IS_ + o0 + tmg * 4 + i) * C_ +
                  n0 + tsg * 2] = q;
  }
}

// ------------------------------------------------- k2b: reduce 8 partials
__global__ __launch_bounds__(256) void k2b_reduce(float* __restrict__ ws) {
  int f = blockIdx.x * 256 + threadIdx.x;   // 0..65535 float4 slots
  const float4* ap = (const float4*)(ws + OFF_AP);
  float4* a = (float4*)(ws + OFF_A);
  float4 s = ap[f];
#pragma unroll
  for (int p = 1; p < 8; ++p) {
    float4 t = ap[f + p * 65536];
    s.x += t.x; s.y += t.y; s.z += t.z; s.w += t.w;
  }
  a[f] = s;
}

// ---------------- k3: g = relu(bn(A0 @ thetaT_b + A1 @ phiT_b))  [b][o][s]
// grid (32 s, 4 o, 8 b), 512 threads. 2 chunks (one per mat), T14 staged.
__global__ __launch_bounds__(512) void k3_g(float* __restrict__ ws) {
  __shared__ float lw[64 * 68];   // [o][c] pad 68
  __shared__ float lx[64 * 66];   // [s][c] pad 66
  const int tid = threadIdx.x;
  const int s0  = blockIdx.x * 64;
  const int o0  = blockIdx.y * 64;
  const int b   = blockIdx.z;
  const int r0 = tid >> 4;
  const int c0 = tid & 15;
  const int tmg = tid >> 4;       // 0..31 -> 2 o-rows
  const int tsg = tid & 15;       // 0..15 -> 4 s-cols stride 16
  const float* A   = ws + OFF_A;
  const float* cst = ws + OFF_CONST;
  float4 areg[2], treg[2];
  float acc[2][4] = {};

#define K3_LOAD(MAT) do {                                                     \
    const float* Tsrc = ws + ((MAT) ? OFF_PHT : OFF_THT);                     \
    _Pragma("unroll")                                                         \
    for (int p = 0; p < 2; ++p) {                                             \
      int row = r0 + 32 * p;                                                  \
      areg[p] = *(const float4*)&A[((size_t)(MAT) * IS_ + o0 + row) * C_ +    \
                                   b * IC_ + c0 * 4];                         \
      treg[p] = *(const float4*)&Tsrc[(size_t)(s0 + row) * C_ +               \
                                      b * IC_ + c0 * 4];                      \
    } } while (0)

  K3_LOAD(0);
  for (int c = 0; c < 2; ++c) {
    if (c) __syncthreads();
#pragma unroll
    for (int p = 0; p < 2; ++p) {
      int row = r0 + 32 * p;
      *(float4*)&lw[row * 68 + c0 * 4] = areg[p];
      *(float4*)&lx[row * 66 + c0 * 4] = treg[p];
    }
    __syncthreads();
    if (c < 1) K3_LOAD(1);
#pragma unroll 4
    for (int k4 = 0; k4 < 16; ++k4) {
      float4 av[2], bt[4];
#pragma unroll
      for (int i = 0; i < 2; ++i)
        av[i] = *(const float4*)&lw[(tmg * 2 + i) * 68 + k4 * 4];
#pragma unroll
      for (int j = 0; j < 4; ++j)
        bt[j] = *(const float4*)&lx[(tsg + 16 * j) * 66 + k4 * 4];
#pragma unroll
      for (int i = 0; i < 2; ++i) {
#pragma unroll
        for (int j = 0; j < 4; ++j) {
          acc[i][j] += av[i].x * bt[j].x + av[i].y * bt[j].y +
                       av[i].z * bt[j].z + av[i].w * bt[j].w;
        }
      }
    }
  }
#undef K3_LOAD
  float* g = ws + OFF_G;
#pragma unroll
  for (int i = 0; i < 2; ++i) {
    int o = o0 + tmg * 2 + i;
    float sc = cst[256 + o], bi = cst[512 + o];
#pragma unroll
    for (int j = 0; j < 4; ++j) {
      float v = sc * acc[i][j] + bi;
      g[((size_t)b * IS_ + o) * S_ + s0 + tsg + 16 * j] = v > 0.f ? v : 0.f;
    }
  }
}

// --------- k4a: y=relu(bn(W1@g)); ys=bn(W2@y); gate=sigmoid -> ws[GATE]
__global__ __launch_bounds__(256) void k4a_gate(
    const float* __restrict__ W1, const float* __restrict__ W2,
    float* __restrict__ ws) {
  __shared__ float lds_g[128 * 65];
  __shared__ float lds_y[32 * 65];
  const int tid = threadIdx.x;
  const int s0  = blockIdx.x * 64;
  const int b   = blockIdx.y;
  const int s   = tid & 63;
  const int og  = tid >> 6;
  const float* cst  = ws + OFF_CONST;
  const float* gsrc = ws + OFF_G + (size_t)b * IS_ * S_;
  float acc[8] = {};

  for (int half = 0; half < 2; ++half) {
    __syncthreads();
#pragma unroll
    for (int j = 0; j < 32; ++j) {
      int idx = tid + j * 256;       // 8192 = 128 x 64
      lds_g[(idx >> 6) * 65 + (idx & 63)] =
          gsrc[(size_t)(half * 128 + (idx >> 6)) * S_ + s0 + (idx & 63)];
    }
    __syncthreads();
#pragma unroll
    for (int c4 = 0; c4 < 32; ++c4) {
      float g0 = lds_g[(c4 * 4 + 0) * 65 + s];
      float g1 = lds_g[(c4 * 4 + 1) * 65 + s];
      float g2 = lds_g[(c4 * 4 + 2) * 65 + s];
      float g3 = lds_g[(c4 * 4 + 3) * 65 + s];
#pragma unroll
      for (int j = 0; j < 8; ++j) {
        const float4 w = *(const float4*)&W1[(size_t)(og * 8 + j) * IS_ + half * 128 + c4 * 4];
        acc[j] += g0 * w.x + g1 * w.y + g2 * w.z + g3 * w.w;
      }
    }
  }
#pragma unroll
  for (int j = 0; j < 8; ++j) {
    int o = og * 8 + j;
    float v = cst[768 + o] * acc[j] + cst[800 + o];
    lds_y[o * 65 + s] = v > 0.f ? v : 0.f;
  }
  __syncthreads();
  if (tid < 64) {
    float sum = 0.f;
#pragma unroll
    for (int c = 0; c < 32; ++c) sum += W2[c] * lds_y[c * 65 + tid];
    float ys = cst[832] * sum + cst[833];
    ws[OFF_GATE + (size_t)b * S_ + s0 + tid] = 1.f / (1.f + expf(-ys));
  }
}

// --------------------------- k4b: out = x * gate  (pure stream, float4)
__global__ __launch_bounds__(256) void k4b_mul(
    const float* __restrict__ x, const float* __restrict__ ws,
    float* __restrict__ out) {
  const float* gate = ws + OFF_GATE;
  size_t i0 = (size_t)blockIdx.x * 256 + threadIdx.x;
  for (size_t f = i0; f < 2097152; f += 524288) {  // 8*512*2048/4 float4s
    size_t elem = f * 4;
    int b = (int)(elem >> 20);          // / (512*2048)
    int s = (int)(elem & 2047);
    float4 xv = *(const float4*)&x[elem];
    float4 gv = *(const float4*)&gate[(size_t)b * S_ + s];
    float4 ov;
    ov.x = xv.x * gv.x; ov.y = xv.y * gv.y;
    ov.z = xv.z * gv.z; ov.w = xv.w * gv.w;
    *(float4*)&out[elem] = ov;
  }
}

// ---------------------------------------------------------------------------
extern "C" void kernel_launch(void* const* d_in, const int* in_sizes, int n_in,
                              void* d_out, int out_size, void* d_ws, size_t ws_size,
                              hipStream_t stream) {
  const float* x   = (const float*)d_in[0];
  const float* Wt  = (const float*)d_in[1];
  const float* tg  = (const float*)d_in[2];
  const float* tb  = (const float*)d_in[3];
  const float* tm  = (const float*)d_in[4];
  const float* tv  = (const float*)d_in[5];
  const float* Wp  = (const float*)d_in[6];
  const float* pg  = (const float*)d_in[7];
  const float* pb  = (const float*)d_in[8];
  const float* pm  = (const float*)d_in[9];
  const float* pv  = (const float*)d_in[10];
  const float* Wgg = (const float*)d_in[11];
  const float* ggg = (const float*)d_in[12];
  const float* ggb = (const float*)d_in[13];
  const float* ggm = (const float*)d_in[14];
  const float* ggv = (const float*)d_in[15];
  const float* W1  = (const float*)d_in[16];
  const float* w1g = (const float*)d_in[17];
  const float* w1b = (const float*)d_in[18];
  const float* w1m = (const float*)d_in[19];
  const float* w1v = (const float*)d_in[20];
  const float* W2  = (const float*)d_in[21];
  const float* w2g = (const float*)d_in[22];
  const float* w2b = (const float*)d_in[23];
  const float* w2m = (const float*)d_in[24];
  const float* w2v = (const float*)d_in[25];
  float* ws  = (float*)d_ws;
  float* out = (float*)d_out;

  k0_consts<<<1, 256, 0, stream>>>(tg, tb, tm, tv, pg, pb, pm, pv,
                                   ggg, ggb, ggm, ggv, w1g, w1b, w1m, w1v,
                                   w2g, w2b, w2m, w2v, ws + OFF_CONST);
  k1_theta_phi<<<dim3(S_ / 64, B_, 2), 512, 0, stream>>>(
      x, Wt, Wp, ws + OFF_CONST, ws + OFF_THT, ws + OFF_PHT);
  k2_factor<<<dim3(8, 4, 16), 512, 0, stream>>>(Wgg, ws, ws + OFF_AP);
  k2b_reduce<<<256, 256, 0, stream>>>(ws);
  k3_g<<<dim3(32, 4, 8), 512, 0, stream>>>(ws);
  k4a_gate<<<dim3(32, 8), 256, 0, stream>>>(W1, W2, ws);
  k4b_mul<<<2048, 256, 0, stream>>>(x, ws, out);
}

// Round 5
// 107.475 us; speedup vs baseline: 1.8239x; 1.8239x over previous
//
#include <hip/hip_runtime.h>
#include <math.h>

#define EPS 1e-5f
#define B_ 8
#define C_ 512
#define S_ 2048
#define IC_ 64
#define IS_ 256
#define DS_ 32

// ws layout (float offsets)
#define OFF_CONST 0
#define OFF_THT   1024                       // thetaT [S_][512]: [t][b*64+c]
#define OFF_PHT   (OFF_THT + S_*C_)          // phiT   [S_][512]
#define OFF_A     (OFF_PHT + S_*C_)          // A [2][256][512]
#define OFF_G     (OFF_A + 2*IS_*C_)         // g [8][256][2048]
#define OFF_AP    OFF_G                      // partials [8][2][256][512] (aliased; dead before k3)
#define OFF_GATE  (OFF_G + B_*IS_*S_)        // gate [8][2048]

using short8 = __attribute__((ext_vector_type(8))) short;
using f32x4  = __attribute__((ext_vector_type(4))) float;

__device__ __forceinline__ short f2bf(float f) {
  union { float f; unsigned u; } v; v.f = f;
  unsigned r = v.u + 0x7fffu + ((v.u >> 16) & 1u);
  return (short)(r >> 16);
}
__device__ __forceinline__ float bf2f(short h) {
  union { unsigned u; float f; } v;
  v.u = ((unsigned)(unsigned short)h) << 16;
  return v.f;
}
// split f into hi+lo bf16 pair: f = hi + lo + O(2^-18 * f)
__device__ __forceinline__ void split8arr(const float* f, short8& hi, short8& lo) {
#pragma unroll
  for (int e = 0; e < 8; ++e) {
    short h = f2bf(f[e]);
    hi[e] = h;
    lo[e] = f2bf(f[e] - bf2f(h));
  }
}
__device__ __forceinline__ void split44(float4 a, float4 b, short8& hi, short8& lo) {
  float f[8] = {a.x, a.y, a.z, a.w, b.x, b.y, b.z, b.w};
  split8arr(f, hi, lo);
}

// ---------------------------------------------------------------- k0: fold BN
__global__ __launch_bounds__(256) void k0_consts(
    const float* tg, const float* tb, const float* tm, const float* tv,
    const float* pg, const float* pb, const float* pm, const float* pv,
    const float* gg, const float* gb, const float* gm, const float* gv,
    const float* w1g, const float* w1b, const float* w1m, const float* w1v,
    const float* w2g, const float* w2b, const float* w2m, const float* w2v,
    float* cst) {
  int i = threadIdx.x;
  if (i < 64) {
    float a = tg[i] * rsqrtf(tv[i] + EPS);
    cst[i] = a; cst[64 + i] = tb[i] - tm[i] * a;
    float ap = pg[i] * rsqrtf(pv[i] + EPS);
    cst[128 + i] = ap; cst[192 + i] = pb[i] - pm[i] * ap;
  }
  if (i < 256) {
    float a = gg[i] * rsqrtf(gv[i] + EPS);
    cst[256 + i] = a; cst[512 + i] = gb[i] - gm[i] * a;
  }
  if (i < 32) {
    float a = w1g[i] * rsqrtf(w1v[i] + EPS);
    cst[768 + i] = a; cst[800 + i] = w1b[i] - w1m[i] * a;
  }
  if (i == 0) {
    float a = w2g[0] * rsqrtf(w2v[0] + EPS);
    cst[832] = a; cst[833] = w2b[0] - w2m[0] * a;
  }
}

// --------------- k1: theta/phi = relu(bn(W @ x)), split-bf16 MFMA 16x16x32
// grid (32 s-tiles, 8 b), block 256 = 4 waves = (mat, s-half32).
// D[m][s]: A = W [m][k], B = x [k][s] (k-major staged via column reads).
__global__ __launch_bounds__(256) void k1_mfma(
    const float* __restrict__ x, const float* __restrict__ Wt,
    const float* __restrict__ Wp, const float* __restrict__ cst,
    float* __restrict__ thetaT, float* __restrict__ phiT) {
  __shared__ short xh[64 * 72], xlo[64 * 72];       // [s][k]
  __shared__ short wh[2][64 * 72], wlo[2][64 * 72]; // [mat][m][k]
  const int tid  = threadIdx.x;
  const int lane = tid & 63;
  const int wv   = tid >> 6;
  const int mat  = wv >> 1, sh = wv & 1;
  const int s0   = blockIdx.x * 64;
  const int b    = blockIdx.y;
  const float* xb = x + (size_t)b * C_ * S_;
  const int xs = tid & 63;             // staging: s-lane
  const int xo = tid >> 6;             // staging: octet group (octs xo, xo+4)

  float  xr[16];
  float4 wr[4][2];
  f32x4  acc[4][2];
#pragma unroll
  for (int i = 0; i < 4; ++i)
#pragma unroll
    for (int j = 0; j < 2; ++j) acc[i][j] = (f32x4){0.f, 0.f, 0.f, 0.f};

#define K1_PF(KC) do {                                                        \
    _Pragma("unroll")                                                         \
    for (int h = 0; h < 2; ++h) {                                             \
      int oct = xo + h * 4;                                                   \
      _Pragma("unroll")                                                       \
      for (int e = 0; e < 8; ++e)                                             \
        xr[h * 8 + e] = xb[(size_t)((KC) + oct * 8 + e) * S_ + s0 + xs];      \
    }                                                                         \
    _Pragma("unroll")                                                         \
    for (int p = 0; p < 4; ++p) {                                             \
      int q = tid + p * 256;                                                  \
      int mq = q >> 9, m = (q >> 3) & 63, oct = q & 7;                        \
      const float* Wm = mq ? Wp : Wt;                                         \
      wr[p][0] = *(const float4*)&Wm[(size_t)m * C_ + (KC) + oct * 8];        \
      wr[p][1] = *(const float4*)&Wm[(size_t)m * C_ + (KC) + oct * 8 + 4];    \
    } } while (0)

  K1_PF(0);
  for (int c = 0; c < 8; ++c) {
    if (c) __syncthreads();
#pragma unroll
    for (int h = 0; h < 2; ++h) {
      int oct = xo + h * 4;
      short8 hi, lo; split8arr(&xr[h * 8], hi, lo);
      *(short8*)&xh[xs * 72 + oct * 8]  = hi;
      *(short8*)&xlo[xs * 72 + oct * 8] = lo;
    }
#pragma unroll
    for (int p = 0; p < 4; ++p) {
      int q = tid + p * 256;
      int mq = q >> 9, m = (q >> 3) & 63, oct = q & 7;
      short8 hi, lo; split44(wr[p][0], wr[p][1], hi, lo);
      *(short8*)&wh[mq][m * 72 + oct * 8]  = hi;
      *(short8*)&wlo[mq][m * 72 + oct * 8] = lo;
    }
    __syncthreads();
    if (c < 7) K1_PF((c + 1) * 64);
#pragma unroll
    for (int ks = 0; ks < 2; ++ks) {
      const int ko = ks * 32 + ((lane >> 4) << 3);
      short8 bh[2], bl[2], ah[4], al[4];
#pragma unroll
      for (int sj = 0; sj < 2; ++sj) {
        int r = (sh * 32 + sj * 16 + (lane & 15)) * 72 + ko;
        bh[sj] = *(const short8*)&xh[r];
        bl[sj] = *(const short8*)&xlo[r];
      }
#pragma unroll
      for (int mi = 0; mi < 4; ++mi) {
        int r = (mi * 16 + (lane & 15)) * 72 + ko;
        ah[mi] = *(const short8*)&wh[mat][r];
        al[mi] = *(const short8*)&wlo[mat][r];
      }
#pragma unroll
      for (int mi = 0; mi < 4; ++mi)
#pragma unroll
        for (int sj = 0; sj < 2; ++sj) {
          acc[mi][sj] = __builtin_amdgcn_mfma_f32_16x16x32_bf16(
              ah[mi], bh[sj], acc[mi][sj], 0, 0, 0);
          acc[mi][sj] = __builtin_amdgcn_mfma_f32_16x16x32_bf16(
              ah[mi], bl[sj], acc[mi][sj], 0, 0, 0);
          acc[mi][sj] = __builtin_amdgcn_mfma_f32_16x16x32_bf16(
              al[mi], bh[sj], acc[mi][sj], 0, 0, 0);
        }
    }
  }
#undef K1_PF
  const float* ac = cst + mat * 128;
  float* outT = mat ? phiT : thetaT;
#pragma unroll
  for (int mi = 0; mi < 4; ++mi) {
    const int m = mi * 16 + ((lane >> 4) << 2);
    float4 sc4 = *(const float4*)&ac[m];
    float4 bi4 = *(const float4*)&ac[64 + m];
#pragma unroll
    for (int sj = 0; sj < 2; ++sj) {
      int s = s0 + sh * 32 + sj * 16 + (lane & 15);
      float4 q;
      q.x = fmaxf(sc4.x * acc[mi][sj][0] + bi4.x, 0.f);
      q.y = fmaxf(sc4.y * acc[mi][sj][1] + bi4.y, 0.f);
      q.z = fmaxf(sc4.z * acc[mi][sj][2] + bi4.z, 0.f);
      q.w = fmaxf(sc4.w * acc[mi][sj][3] + bi4.w, 0.f);
      *(float4*)&outT[(size_t)s * C_ + b * IC_ + m] = q;
    }
  }
}

// ---- k2: Ap[part][mat][o][n] = Wgg[o, mat*S + t] @ (mat? thetaT : phiT)[t][n]
// grid (8 n-tiles, 2 o-tiles, mat*8+part), block 256 = 4 waves (o-quarter).
// D[n][o]: A = Bm^T [n][t] (column-staged), B = Wgg [o][t] k-major rows.
__global__ __launch_bounds__(256) void k2_mfma(
    const float* __restrict__ Wgg, const float* __restrict__ ws,
    float* __restrict__ Ap) {
  __shared__ short nh[64 * 72], nlo[64 * 72];     // [n][t]
  __shared__ short oh[128 * 72], olo[128 * 72];   // [o][t]
  const int tid  = threadIdx.x;
  const int lane = tid & 63;
  const int wv   = tid >> 6;
  const int n0    = blockIdx.x * 64;
  const int o_blk = blockIdx.y * 128;
  const int mat   = blockIdx.z >> 3;
  const int part  = blockIdx.z & 7;
  const int t0 = part * 256;
  const float* Bm = ws + (mat ? OFF_THT : OFF_PHT);
  const int xs = tid & 63;
  const int xo = tid >> 6;

  float  ar[16];
  float4 br[4][2];
  f32x4  acc[4][2];
#pragma unroll
  for (int i = 0; i < 4; ++i)
#pragma unroll
    for (int j = 0; j < 2; ++j) acc[i][j] = (f32x4){0.f, 0.f, 0.f, 0.f};

#define K2_PF(KC) do {                                                        \
    _Pragma("unroll")                                                         \
    for (int h = 0; h < 2; ++h) {                                             \
      int oct = xo + h * 4;                                                   \
      _Pragma("unroll")                                                       \
      for (int e = 0; e < 8; ++e)                                             \
        ar[h * 8 + e] = Bm[(size_t)(t0 + (KC) + oct * 8 + e) * C_ + n0 + xs]; \
    }                                                                         \
    _Pragma("unroll")                                                         \
    for (int p = 0; p < 4; ++p) {                                             \
      int q = tid + p * 256;                                                  \
      int o = q >> 3, oct = q & 7;                                            \
      const float* src = &Wgg[(size_t)(o_blk + o) * (2 * S_) + mat * S_ +     \
                              t0 + (KC) + oct * 8];                           \
      br[p][0] = *(const float4*)src;                                         \
      br[p][1] = *(const float4*)(src + 4);                                   \
    } } while (0)

  K2_PF(0);
  for (int c = 0; c < 4; ++c) {
    if (c) __syncthreads();
#pragma unroll
    for (int h = 0; h < 2; ++h) {
      int oct = xo + h * 4;
      short8 hi, lo; split8arr(&ar[h * 8], hi, lo);
      *(short8*)&nh[xs * 72 + oct * 8]  = hi;
      *(short8*)&nlo[xs * 72 + oct * 8] = lo;
    }
#pragma unroll
    for (int p = 0; p < 4; ++p) {
      int q = tid + p * 256;
      int o = q >> 3, oct = q & 7;
      short8 hi, lo; split44(br[p][0], br[p][1], hi, lo);
      *(short8*)&oh[o * 72 + oct * 8]  = hi;
      *(short8*)&olo[o * 72 + oct * 8] = lo;
    }
    __syncthreads();
    if (c < 3) K2_PF((c + 1) * 64);
#pragma unroll
    for (int ks = 0; ks < 2; ++ks) {
      const int ko = ks * 32 + ((lane >> 4) << 3);
      short8 ah[4], al[4], bh[2], bl[2];
#pragma unroll
      for (int ni = 0; ni < 4; ++ni) {
        int r = (ni * 16 + (lane & 15)) * 72 + ko;
        ah[ni] = *(const short8*)&nh[r];
        al[ni] = *(const short8*)&nlo[r];
      }
#pragma unroll
      for (int oj = 0; oj < 2; ++oj) {
        int r = (wv * 32 + oj * 16 + (lane & 15)) * 72 + ko;
        bh[oj] = *(const short8*)&oh[r];
        bl[oj] = *(const short8*)&olo[r];
      }
#pragma unroll
      for (int ni = 0; ni < 4; ++ni)
#pragma unroll
        for (int oj = 0; oj < 2; ++oj) {
          acc[ni][oj] = __builtin_amdgcn_mfma_f32_16x16x32_bf16(
              ah[ni], bh[oj], acc[ni][oj], 0, 0, 0);
          acc[ni][oj] = __builtin_amdgcn_mfma_f32_16x16x32_bf16(
              ah[ni], bl[oj], acc[ni][oj], 0, 0, 0);
          acc[ni][oj] = __builtin_amdgcn_mfma_f32_16x16x32_bf16(
              al[ni], bh[oj], acc[ni][oj], 0, 0, 0);
        }
    }
  }
#undef K2_PF
#pragma unroll
  for (int ni = 0; ni < 4; ++ni) {
    const int nq = n0 + ni * 16 + ((lane >> 4) << 2);
#pragma unroll
    for (int oj = 0; oj < 2; ++oj) {
      int o = o_blk + wv * 32 + oj * 16 + (lane & 15);
      float4 q;
      q.x = acc[ni][oj][0]; q.y = acc[ni][oj][1];
      q.z = acc[ni][oj][2]; q.w = acc[ni][oj][3];
      *(float4*)&Ap[((size_t)(part * 2 + mat) * IS_ + o) * C_ + nq] = q;
    }
  }
}

// ------------------------------------------------- k2b: reduce 8 partials
__global__ __launch_bounds__(256) void k2b_reduce(float* __restrict__ ws) {
  int f = blockIdx.x * 256 + threadIdx.x;   // 0..65535 float4 slots
  const float4* ap = (const float4*)(ws + OFF_AP);
  float4* a = (float4*)(ws + OFF_A);
  float4 s = ap[f];
#pragma unroll
  for (int p = 1; p < 8; ++p) {
    float4 t = ap[f + p * 65536];
    s.x += t.x; s.y += t.y; s.z += t.z; s.w += t.w;
  }
  a[f] = s;
}

// -------- k3: g[b][o][s] = relu(bn(A0 @ thetaT_b + A1 @ phiT_b)), split-bf16
// grid (32 s-tiles, 2 o-tiles, 8 b), block 256 = 4 waves (o-quarter).
// D[s][o]: A = thetaT/phiT [s][c] rows, B = Acomb [o][c] rows.
// Contraction: 2 chunks of K=64 — chunk 0 = (A0, theta), chunk 1 = (A1, phi).
// Per-batch channel slice is ONLY c in [0,64) at column b*IC_ (round-4 bug).
__global__ __launch_bounds__(256) void k3_mfma(float* __restrict__ ws) {
  __shared__ short th[64 * 72], tlo[64 * 72];     // [s][c]
  __shared__ short ohh[128 * 72], olo[128 * 72];  // [o][c]
  const int tid  = threadIdx.x;
  const int lane = tid & 63;
  const int wv   = tid >> 6;
  const int s0    = blockIdx.x * 64;
  const int o_blk = blockIdx.y * 128;
  const int b     = blockIdx.z;
  const float* A   = ws + OFF_A;
  const float* cst = ws + OFF_CONST;

  float4 ar[2][2];
  float4 br[4][2];
  f32x4  acc[4][2];
#pragma unroll
  for (int i = 0; i < 4; ++i)
#pragma unroll
    for (int j = 0; j < 2; ++j) acc[i][j] = (f32x4){0.f, 0.f, 0.f, 0.f};

#define K3_PF(MAT) do {                                                       \
    const float* Tsrc = ws + ((MAT) ? OFF_PHT : OFF_THT);                     \
    _Pragma("unroll")                                                         \
    for (int p = 0; p < 2; ++p) {                                             \
      int q = tid + p * 256;                                                  \
      int sl = q >> 3, oct = q & 7;                                           \
      const float* src = &Tsrc[(size_t)(s0 + sl) * C_ + b * IC_ + oct * 8];   \
      ar[p][0] = *(const float4*)src;                                         \
      ar[p][1] = *(const float4*)(src + 4);                                   \
    }                                                                         \
    _Pragma("unroll")                                                         \
    for (int p = 0; p < 4; ++p) {                                             \
      int q = tid + p * 256;                                                  \
      int o = q >> 3, oct = q & 7;                                            \
      const float* src = &A[((size_t)(MAT) * IS_ + o_blk + o) * C_ +          \
                            b * IC_ + oct * 8];                               \
      br[p][0] = *(const float4*)src;                                         \
      br[p][1] = *(const float4*)(src + 4);                                   \
    } } while (0)

  K3_PF(0);
  for (int c = 0; c < 2; ++c) {
    if (c) __syncthreads();
#pragma unroll
    for (int p = 0; p < 2; ++p) {
      int q = tid + p * 256;
      int sl = q >> 3, oct = q & 7;
      short8 hi, lo; split44(ar[p][0], ar[p][1], hi, lo);
      *(short8*)&th[sl * 72 + oct * 8]  = hi;
      *(short8*)&tlo[sl * 72 + oct * 8] = lo;
    }
#pragma unroll
    for (int p = 0; p < 4; ++p) {
      int q = tid + p * 256;
      int o = q >> 3, oct = q & 7;
      short8 hi, lo; split44(br[p][0], br[p][1], hi, lo);
      *(short8*)&ohh[o * 72 + oct * 8] = hi;
      *(short8*)&olo[o * 72 + oct * 8] = lo;
    }
    __syncthreads();
    if (c < 1) K3_PF(1);
#pragma unroll
    for (int ks = 0; ks < 2; ++ks) {
      const int ko = ks * 32 + ((lane >> 4) << 3);
      short8 ah[4], al[4], bh[2], bl[2];
#pragma unroll
      for (int si = 0; si < 4; ++si) {
        int r = (si * 16 + (lane & 15)) * 72 + ko;
        ah[si] = *(const short8*)&th[r];
        al[si] = *(const short8*)&tlo[r];
      }
#pragma unroll
      for (int oj = 0; oj < 2; ++oj) {
        int r = (wv * 32 + oj * 16 + (lane & 15)) * 72 + ko;
        bh[oj] = *(const short8*)&ohh[r];
        bl[oj] = *(const short8*)&olo[r];
      }
#pragma unroll
      for (int si = 0; si < 4; ++si)
#pragma unroll
        for (int oj = 0; oj < 2; ++oj) {
          acc[si][oj] = __builtin_amdgcn_mfma_f32_16x16x32_bf16(
              ah[si], bh[oj], acc[si][oj], 0, 0, 0);
          acc[si][oj] = __builtin_amdgcn_mfma_f32_16x16x32_bf16(
              ah[si], bl[oj], acc[si][oj], 0, 0, 0);
          acc[si][oj] = __builtin_amdgcn_mfma_f32_16x16x32_bf16(
              al[si], bh[oj], acc[si][oj], 0, 0, 0);
        }
    }
  }
#undef K3_PF
  float* g = ws + OFF_G;
#pragma unroll
  for (int oj = 0; oj < 2; ++oj) {
    int o = o_blk + wv * 32 + oj * 16 + (lane & 15);
    float sc = cst[256 + o], bi = cst[512 + o];
#pragma unroll
    for (int si = 0; si < 4; ++si) {
      int sq = s0 + si * 16 + ((lane >> 4) << 2);
      float4 q;
      q.x = fmaxf(sc * acc[si][oj][0] + bi, 0.f);
      q.y = fmaxf(sc * acc[si][oj][1] + bi, 0.f);
      q.z = fmaxf(sc * acc[si][oj][2] + bi, 0.f);
      q.w = fmaxf(sc * acc[si][oj][3] + bi, 0.f);
      *(float4*)&g[((size_t)b * IS_ + o) * S_ + sq] = q;
    }
  }
}

// --------- k4a: y=relu(bn(W1@g)); ys=bn(W2@y); gate=sigmoid -> ws[GATE]
__global__ __launch_bounds__(256) void k4a_gate(
    const float* __restrict__ W1, const float* __restrict__ W2,
    float* __restrict__ ws) {
  __shared__ float lds_g[128 * 65];
  __shared__ float lds_y[32 * 65];
  const int tid = threadIdx.x;
  const int s0  = blockIdx.x * 64;
  const int b   = blockIdx.y;
  const int s   = tid & 63;
  const int og  = tid >> 6;
  const float* cst  = ws + OFF_CONST;
  const float* gsrc = ws + OFF_G + (size_t)b * IS_ * S_;
  float acc[8] = {};

  for (int half = 0; half < 2; ++half) {
    __syncthreads();
#pragma unroll
    for (int j = 0; j < 32; ++j) {
      int idx = tid + j * 256;       // 8192 = 128 x 64
      lds_g[(idx >> 6) * 65 + (idx & 63)] =
          gsrc[(size_t)(half * 128 + (idx >> 6)) * S_ + s0 + (idx & 63)];
    }
    __syncthreads();
#pragma unroll
    for (int c4 = 0; c4 < 32; ++c4) {
      float g0 = lds_g[(c4 * 4 + 0) * 65 + s];
      float g1 = lds_g[(c4 * 4 + 1) * 65 + s];
      float g2 = lds_g[(c4 * 4 + 2) * 65 + s];
      float g3 = lds_g[(c4 * 4 + 3) * 65 + s];
#pragma unroll
      for (int j = 0; j < 8; ++j) {
        const float4 w = *(const float4*)&W1[(size_t)(og * 8 + j) * IS_ + half * 128 + c4 * 4];
        acc[j] += g0 * w.x + g1 * w.y + g2 * w.z + g3 * w.w;
      }
    }
  }
#pragma unroll
  for (int j = 0; j < 8; ++j) {
    int o = og * 8 + j;
    float v = cst[768 + o] * acc[j] + cst[800 + o];
    lds_y[o * 65 + s] = v > 0.f ? v : 0.f;
  }
  __syncthreads();
  if (tid < 64) {
    float sum = 0.f;
#pragma unroll
    for (int c = 0; c < 32; ++c) sum += W2[c] * lds_y[c * 65 + tid];
    float ys = cst[832] * sum + cst[833];
    ws[OFF_GATE + (size_t)b * S_ + s0 + tid] = 1.f / (1.f + expf(-ys));
  }
}

// --------------------------- k4b: out = x * gate  (pure stream, float4)
__global__ __launch_bounds__(256) void k4b_mul(
    const float* __restrict__ x, const float* __restrict__ ws,
    float* __restrict__ out) {
  const float* gate = ws + OFF_GATE;
  size_t i0 = (size_t)blockIdx.x * 256 + threadIdx.x;
  for (size_t f = i0; f < 2097152; f += 524288) {  // 8*512*2048/4 float4s
    size_t elem = f * 4;
    int b = (int)(elem >> 20);          // / (512*2048)
    int s = (int)(elem & 2047);
    float4 xv = *(const float4*)&x[elem];
    float4 gv = *(const float4*)&gate[(size_t)b * S_ + s];
    float4 ov;
    ov.x = xv.x * gv.x; ov.y = xv.y * gv.y;
    ov.z = xv.z * gv.z; ov.w = xv.w * gv.w;
    *(float4*)&out[elem] = ov;
  }
}

// ---------------------------------------------------------------------------
extern "C" void kernel_launch(void* const* d_in, const int* in_sizes, int n_in,
                              void* d_out, int out_size, void* d_ws, size_t ws_size,
                              hipStream_t stream) {
  const float* x   = (const float*)d_in[0];
  const float* Wt  = (const float*)d_in[1];
  const float* tg  = (const float*)d_in[2];
  const float* tb  = (const float*)d_in[3];
  const float* tm  = (const float*)d_in[4];
  const float* tv  = (const float*)d_in[5];
  const float* Wp  = (const float*)d_in[6];
  const float* pg  = (const float*)d_in[7];
  const float* pb  = (const float*)d_in[8];
  const float* pm  = (const float*)d_in[9];
  const float* pv  = (const float*)d_in[10];
  const float* Wgg = (const float*)d_in[11];
  const float* ggg = (const float*)d_in[12];
  const float* ggb = (const float*)d_in[13];
  const float* ggm = (const float*)d_in[14];
  const float* ggv = (const float*)d_in[15];
  const float* W1  = (const float*)d_in[16];
  const float* w1g = (const float*)d_in[17];
  const float* w1b = (const float*)d_in[18];
  const float* w1m = (const float*)d_in[19];
  const float* w1v = (const float*)d_in[20];
  const float* W2  = (const float*)d_in[21];
  const float* w2g = (const float*)d_in[22];
  const float* w2b = (const float*)d_in[23];
  const float* w2m = (const float*)d_in[24];
  const float* w2v = (const float*)d_in[25];
  float* ws  = (float*)d_ws;
  float* out = (float*)d_out;

  k0_consts<<<1, 256, 0, stream>>>(tg, tb, tm, tv, pg, pb, pm, pv,
                                   ggg, ggb, ggm, ggv, w1g, w1b, w1m, w1v,
                                   w2g, w2b, w2m, w2v, ws + OFF_CONST);
  k1_mfma<<<dim3(32, 8), 256, 0, stream>>>(
      x, Wt, Wp, ws + OFF_CONST, ws + OFF_THT, ws + OFF_PHT);
  k2_mfma<<<dim3(8, 2, 16), 256, 0, stream>>>(Wgg, ws, ws + OFF_AP);
  k2b_reduce<<<256, 256, 0, stream>>>(ws);
  k3_mfma<<<dim3(32, 2, 8), 256, 0, stream>>>(ws);
  k4a_gate<<<dim3(32, 8), 256, 0, stream>>>(W1, W2, ws);
  k4b_mul<<<2048, 256, 0, stream>>>(x, ws, out);
}

// Round 6
// 86.633 us; speedup vs baseline: 2.2626x; 1.2406x over previous
//
#include <hip/hip_runtime.h>
#include <math.h>

#define EPS 1e-5f
#define B_ 8
#define C_ 512
#define S_ 2048
#define IC_ 64
#define IS_ 256
#define DS_ 32

// ws layout (float offsets)
#define OFF_CONST 0
#define OFF_THT   1024                       // thetaT [S_][512]: [t][b*64+c]
#define OFF_PHT   (OFF_THT + S_*C_)          // phiT   [S_][512]
#define OFF_A     (OFF_PHT + S_*C_)          // A [2][256][512]
#define OFF_G     (OFF_A + 2*IS_*C_)         // g [8][256][2048]
#define OFF_AP    OFF_G                      // partials [8][2][256][512] (aliased; dead before k3)
#define OFF_GATE  (OFF_G + B_*IS_*S_)        // gate [8][2048]

using short8 = __attribute__((ext_vector_type(8))) short;
using f32x4  = __attribute__((ext_vector_type(4))) float;

__device__ __forceinline__ short f2bf(float f) {
  union { float f; unsigned u; } v; v.f = f;
  unsigned r = v.u + 0x7fffu + ((v.u >> 16) & 1u);
  return (short)(r >> 16);
}
__device__ __forceinline__ float bf2f(short h) {
  union { unsigned u; float f; } v;
  v.u = ((unsigned)(unsigned short)h) << 16;
  return v.f;
}
// split f into hi+lo bf16 pair: f = hi + lo + O(2^-18 * f)
__device__ __forceinline__ void split8arr(const float* f, short8& hi, short8& lo) {
#pragma unroll
  for (int e = 0; e < 8; ++e) {
    short h = f2bf(f[e]);
    hi[e] = h;
    lo[e] = f2bf(f[e] - bf2f(h));
  }
}
__device__ __forceinline__ void split44(float4 a, float4 b, short8& hi, short8& lo) {
  float f[8] = {a.x, a.y, a.z, a.w, b.x, b.y, b.z, b.w};
  split8arr(f, hi, lo);
}

// ---------------------------------------------------------------- k0: fold BN
__global__ __launch_bounds__(256) void k0_consts(
    const float* tg, const float* tb, const float* tm, const float* tv,
    const float* pg, const float* pb, const float* pm, const float* pv,
    const float* gg, const float* gb, const float* gm, const float* gv,
    const float* w1g, const float* w1b, const float* w1m, const float* w1v,
    const float* w2g, const float* w2b, const float* w2m, const float* w2v,
    float* cst) {
  int i = threadIdx.x;
  if (i < 64) {
    float a = tg[i] * rsqrtf(tv[i] + EPS);
    cst[i] = a; cst[64 + i] = tb[i] - tm[i] * a;
    float ap = pg[i] * rsqrtf(pv[i] + EPS);
    cst[128 + i] = ap; cst[192 + i] = pb[i] - pm[i] * ap;
  }
  if (i < 256) {
    float a = gg[i] * rsqrtf(gv[i] + EPS);
    cst[256 + i] = a; cst[512 + i] = gb[i] - gm[i] * a;
  }
  if (i < 32) {
    float a = w1g[i] * rsqrtf(w1v[i] + EPS);
    cst[768 + i] = a; cst[800 + i] = w1b[i] - w1m[i] * a;
  }
  if (i == 0) {
    float a = w2g[0] * rsqrtf(w2v[0] + EPS);
    cst[832] = a; cst[833] = w2b[0] - w2m[0] * a;
  }
}

// --------------- k1: theta/phi = relu(bn(W @ x)), split-bf16 MFMA 16x16x32
// grid (32 s-tiles, 8 b), block 256 = 4 waves = (mat, s-half32).
// D[m][s]: A = W [m][k], B = x [k][s] (k-major staged via column reads).
__global__ __launch_bounds__(256) void k1_mfma(
    const float* __restrict__ x, const float* __restrict__ Wt,
    const float* __restrict__ Wp, const float* __restrict__ cst,
    float* __restrict__ thetaT, float* __restrict__ phiT) {
  __shared__ short xh[64 * 72], xlo[64 * 72];       // [s][k]
  __shared__ short wh[2][64 * 72], wlo[2][64 * 72]; // [mat][m][k]
  const int tid  = threadIdx.x;
  const int lane = tid & 63;
  const int wv   = tid >> 6;
  const int mat  = wv >> 1, sh = wv & 1;
  const int s0   = blockIdx.x * 64;
  const int b    = blockIdx.y;
  const float* xb = x + (size_t)b * C_ * S_;
  const int xs = tid & 63;             // staging: s-lane
  const int xo = tid >> 6;             // staging: octet group (octs xo, xo+4)

  float  xr[16];
  float4 wr[4][2];
  f32x4  acc[4][2];
#pragma unroll
  for (int i = 0; i < 4; ++i)
#pragma unroll
    for (int j = 0; j < 2; ++j) acc[i][j] = (f32x4){0.f, 0.f, 0.f, 0.f};

#define K1_PF(KC) do {                                                        \
    _Pragma("unroll")                                                         \
    for (int h = 0; h < 2; ++h) {                                             \
      int oct = xo + h * 4;                                                   \
      _Pragma("unroll")                                                       \
      for (int e = 0; e < 8; ++e)                                             \
        xr[h * 8 + e] = xb[(size_t)((KC) + oct * 8 + e) * S_ + s0 + xs];      \
    }                                                                         \
    _Pragma("unroll")                                                         \
    for (int p = 0; p < 4; ++p) {                                             \
      int q = tid + p * 256;                                                  \
      int mq = q >> 9, m = (q >> 3) & 63, oct = q & 7;                        \
      const float* Wm = mq ? Wp : Wt;                                         \
      wr[p][0] = *(const float4*)&Wm[(size_t)m * C_ + (KC) + oct * 8];        \
      wr[p][1] = *(const float4*)&Wm[(size_t)m * C_ + (KC) + oct * 8 + 4];    \
    } } while (0)

  K1_PF(0);
  for (int c = 0; c < 8; ++c) {
    if (c) __syncthreads();
#pragma unroll
    for (int h = 0; h < 2; ++h) {
      int oct = xo + h * 4;
      short8 hi, lo; split8arr(&xr[h * 8], hi, lo);
      *(short8*)&xh[xs * 72 + oct * 8]  = hi;
      *(short8*)&xlo[xs * 72 + oct * 8] = lo;
    }
#pragma unroll
    for (int p = 0; p < 4; ++p) {
      int q = tid + p * 256;
      int mq = q >> 9, m = (q >> 3) & 63, oct = q & 7;
      short8 hi, lo; split44(wr[p][0], wr[p][1], hi, lo);
      *(short8*)&wh[mq][m * 72 + oct * 8]  = hi;
      *(short8*)&wlo[mq][m * 72 + oct * 8] = lo;
    }
    __syncthreads();
    if (c < 7) K1_PF((c + 1) * 64);
#pragma unroll
    for (int ks = 0; ks < 2; ++ks) {
      const int ko = ks * 32 + ((lane >> 4) << 3);
      short8 bh[2], bl[2], ah[4], al[4];
#pragma unroll
      for (int sj = 0; sj < 2; ++sj) {
        int r = (sh * 32 + sj * 16 + (lane & 15)) * 72 + ko;
        bh[sj] = *(const short8*)&xh[r];
        bl[sj] = *(const short8*)&xlo[r];
      }
#pragma unroll
      for (int mi = 0; mi < 4; ++mi) {
        int r = (mi * 16 + (lane & 15)) * 72 + ko;
        ah[mi] = *(const short8*)&wh[mat][r];
        al[mi] = *(const short8*)&wlo[mat][r];
      }
#pragma unroll
      for (int mi = 0; mi < 4; ++mi)
#pragma unroll
        for (int sj = 0; sj < 2; ++sj) {
          acc[mi][sj] = __builtin_amdgcn_mfma_f32_16x16x32_bf16(
              ah[mi], bh[sj], acc[mi][sj], 0, 0, 0);
          acc[mi][sj] = __builtin_amdgcn_mfma_f32_16x16x32_bf16(
              ah[mi], bl[sj], acc[mi][sj], 0, 0, 0);
          acc[mi][sj] = __builtin_amdgcn_mfma_f32_16x16x32_bf16(
              al[mi], bh[sj], acc[mi][sj], 0, 0, 0);
        }
    }
  }
#undef K1_PF
  const float* ac = cst + mat * 128;
  float* outT = mat ? phiT : thetaT;
#pragma unroll
  for (int mi = 0; mi < 4; ++mi) {
    const int m = mi * 16 + ((lane >> 4) << 2);
    float4 sc4 = *(const float4*)&ac[m];
    float4 bi4 = *(const float4*)&ac[64 + m];
#pragma unroll
    for (int sj = 0; sj < 2; ++sj) {
      int s = s0 + sh * 32 + sj * 16 + (lane & 15);
      float4 q;
      q.x = fmaxf(sc4.x * acc[mi][sj][0] + bi4.x, 0.f);
      q.y = fmaxf(sc4.y * acc[mi][sj][1] + bi4.y, 0.f);
      q.z = fmaxf(sc4.z * acc[mi][sj][2] + bi4.z, 0.f);
      q.w = fmaxf(sc4.w * acc[mi][sj][3] + bi4.w, 0.f);
      *(float4*)&outT[(size_t)s * C_ + b * IC_ + m] = q;
    }
  }
}

// ---- k2: Ap[part][mat][o][n] = Wgg[o, mat*S + t] @ (mat? thetaT : phiT)[t][n]
// grid (8 n-tiles, 2 o-tiles, mat*8+part), block 256 = 4 waves (o-quarter).
// D[n][o]: A = Bm^T [n][t] (column-staged), B = Wgg [o][t] k-major rows.
__global__ __launch_bounds__(256) void k2_mfma(
    const float* __restrict__ Wgg, const float* __restrict__ ws,
    float* __restrict__ Ap) {
  __shared__ short nh[64 * 72], nlo[64 * 72];     // [n][t]
  __shared__ short oh[128 * 72], olo[128 * 72];   // [o][t]
  const int tid  = threadIdx.x;
  const int lane = tid & 63;
  const int wv   = tid >> 6;
  const int n0    = blockIdx.x * 64;
  const int o_blk = blockIdx.y * 128;
  const int mat   = blockIdx.z >> 3;
  const int part  = blockIdx.z & 7;
  const int t0 = part * 256;
  const float* Bm = ws + (mat ? OFF_THT : OFF_PHT);
  const int xs = tid & 63;
  const int xo = tid >> 6;

  float  ar[16];
  float4 br[4][2];
  f32x4  acc[4][2];
#pragma unroll
  for (int i = 0; i < 4; ++i)
#pragma unroll
    for (int j = 0; j < 2; ++j) acc[i][j] = (f32x4){0.f, 0.f, 0.f, 0.f};

#define K2_PF(KC) do {                                                        \
    _Pragma("unroll")                                                         \
    for (int h = 0; h < 2; ++h) {                                             \
      int oct = xo + h * 4;                                                   \
      _Pragma("unroll")                                                       \
      for (int e = 0; e < 8; ++e)                                             \
        ar[h * 8 + e] = Bm[(size_t)(t0 + (KC) + oct * 8 + e) * C_ + n0 + xs]; \
    }                                                                         \
    _Pragma("unroll")                                                         \
    for (int p = 0; p < 4; ++p) {                                             \
      int q = tid + p * 256;                                                  \
      int o = q >> 3, oct = q & 7;                                            \
      const float* src = &Wgg[(size_t)(o_blk + o) * (2 * S_) + mat * S_ +     \
                              t0 + (KC) + oct * 8];                           \
      br[p][0] = *(const float4*)src;                                         \
      br[p][1] = *(const float4*)(src + 4);                                   \
    } } while (0)

  K2_PF(0);
  for (int c = 0; c < 4; ++c) {
    if (c) __syncthreads();
#pragma unroll
    for (int h = 0; h < 2; ++h) {
      int oct = xo + h * 4;
      short8 hi, lo; split8arr(&ar[h * 8], hi, lo);
      *(short8*)&nh[xs * 72 + oct * 8]  = hi;
      *(short8*)&nlo[xs * 72 + oct * 8] = lo;
    }
#pragma unroll
    for (int p = 0; p < 4; ++p) {
      int q = tid + p * 256;
      int o = q >> 3, oct = q & 7;
      short8 hi, lo; split44(br[p][0], br[p][1], hi, lo);
      *(short8*)&oh[o * 72 + oct * 8]  = hi;
      *(short8*)&olo[o * 72 + oct * 8] = lo;
    }
    __syncthreads();
    if (c < 3) K2_PF((c + 1) * 64);
#pragma unroll
    for (int ks = 0; ks < 2; ++ks) {
      const int ko = ks * 32 + ((lane >> 4) << 3);
      short8 ah[4], al[4], bh[2], bl[2];
#pragma unroll
      for (int ni = 0; ni < 4; ++ni) {
        int r = (ni * 16 + (lane & 15)) * 72 + ko;
        ah[ni] = *(const short8*)&nh[r];
        al[ni] = *(const short8*)&nlo[r];
      }
#pragma unroll
      for (int oj = 0; oj < 2; ++oj) {
        int r = (wv * 32 + oj * 16 + (lane & 15)) * 72 + ko;
        bh[oj] = *(const short8*)&oh[r];
        bl[oj] = *(const short8*)&olo[r];
      }
#pragma unroll
      for (int ni = 0; ni < 4; ++ni)
#pragma unroll
        for (int oj = 0; oj < 2; ++oj) {
          acc[ni][oj] = __builtin_amdgcn_mfma_f32_16x16x32_bf16(
              ah[ni], bh[oj], acc[ni][oj], 0, 0, 0);
          acc[ni][oj] = __builtin_amdgcn_mfma_f32_16x16x32_bf16(
              ah[ni], bl[oj], acc[ni][oj], 0, 0, 0);
          acc[ni][oj] = __builtin_amdgcn_mfma_f32_16x16x32_bf16(
              al[ni], bh[oj], acc[ni][oj], 0, 0, 0);
        }
    }
  }
#undef K2_PF
#pragma unroll
  for (int ni = 0; ni < 4; ++ni) {
    const int nq = n0 + ni * 16 + ((lane >> 4) << 2);
#pragma unroll
    for (int oj = 0; oj < 2; ++oj) {
      int o = o_blk + wv * 32 + oj * 16 + (lane & 15);
      float4 q;
      q.x = acc[ni][oj][0]; q.y = acc[ni][oj][1];
      q.z = acc[ni][oj][2]; q.w = acc[ni][oj][3];
      *(float4*)&Ap[((size_t)(part * 2 + mat) * IS_ + o) * C_ + nq] = q;
    }
  }
}

// ------------------------------------------------- k2b: reduce 8 partials
__global__ __launch_bounds__(256) void k2b_reduce(float* __restrict__ ws) {
  int f = blockIdx.x * 256 + threadIdx.x;   // 0..65535 float4 slots
  const float4* ap = (const float4*)(ws + OFF_AP);
  float4* a = (float4*)(ws + OFF_A);
  float4 s = ap[f];
#pragma unroll
  for (int p = 1; p < 8; ++p) {
    float4 t = ap[f + p * 65536];
    s.x += t.x; s.y += t.y; s.z += t.z; s.w += t.w;
  }
  a[f] = s;
}

// -------- k3: g[b][o][s] = relu(bn(A0 @ thetaT_b + A1 @ phiT_b)), split-bf16
// grid (32 s-tiles, 2 o-tiles, 8 b), block 256 = 4 waves (o-quarter).
// D[s][o]: A = thetaT/phiT [s][c] rows, B = Acomb [o][c] rows.
// Contraction: 2 chunks of K=64 — chunk 0 = (A0, theta), chunk 1 = (A1, phi).
__global__ __launch_bounds__(256) void k3_mfma(float* __restrict__ ws) {
  __shared__ short th[64 * 72], tlo[64 * 72];     // [s][c]
  __shared__ short ohh[128 * 72], olo[128 * 72];  // [o][c]
  const int tid  = threadIdx.x;
  const int lane = tid & 63;
  const int wv   = tid >> 6;
  const int s0    = blockIdx.x * 64;
  const int o_blk = blockIdx.y * 128;
  const int b     = blockIdx.z;
  const float* A   = ws + OFF_A;
  const float* cst = ws + OFF_CONST;

  float4 ar[2][2];
  float4 br[4][2];
  f32x4  acc[4][2];
#pragma unroll
  for (int i = 0; i < 4; ++i)
#pragma unroll
    for (int j = 0; j < 2; ++j) acc[i][j] = (f32x4){0.f, 0.f, 0.f, 0.f};

#define K3_PF(MAT) do {                                                       \
    const float* Tsrc = ws + ((MAT) ? OFF_PHT : OFF_THT);                     \
    _Pragma("unroll")                                                         \
    for (int p = 0; p < 2; ++p) {                                             \
      int q = tid + p * 256;                                                  \
      int sl = q >> 3, oct = q & 7;                                           \
      const float* src = &Tsrc[(size_t)(s0 + sl) * C_ + b * IC_ + oct * 8];   \
      ar[p][0] = *(const float4*)src;                                         \
      ar[p][1] = *(const float4*)(src + 4);                                   \
    }                                                                         \
    _Pragma("unroll")                                                         \
    for (int p = 0; p < 4; ++p) {                                             \
      int q = tid + p * 256;                                                  \
      int o = q >> 3, oct = q & 7;                                            \
      const float* src = &A[((size_t)(MAT) * IS_ + o_blk + o) * C_ +          \
                            b * IC_ + oct * 8];                               \
      br[p][0] = *(const float4*)src;                                         \
      br[p][1] = *(const float4*)(src + 4);                                   \
    } } while (0)

  K3_PF(0);
  for (int c = 0; c < 2; ++c) {
    if (c) __syncthreads();
#pragma unroll
    for (int p = 0; p < 2; ++p) {
      int q = tid + p * 256;
      int sl = q >> 3, oct = q & 7;
      short8 hi, lo; split44(ar[p][0], ar[p][1], hi, lo);
      *(short8*)&th[sl * 72 + oct * 8]  = hi;
      *(short8*)&tlo[sl * 72 + oct * 8] = lo;
    }
#pragma unroll
    for (int p = 0; p < 4; ++p) {
      int q = tid + p * 256;
      int o = q >> 3, oct = q & 7;
      short8 hi, lo; split44(br[p][0], br[p][1], hi, lo);
      *(short8*)&ohh[o * 72 + oct * 8] = hi;
      *(short8*)&olo[o * 72 + oct * 8] = lo;
    }
    __syncthreads();
    if (c < 1) K3_PF(1);
#pragma unroll
    for (int ks = 0; ks < 2; ++ks) {
      const int ko = ks * 32 + ((lane >> 4) << 3);
      short8 ah[4], al[4], bh[2], bl[2];
#pragma unroll
      for (int si = 0; si < 4; ++si) {
        int r = (si * 16 + (lane & 15)) * 72 + ko;
        ah[si] = *(const short8*)&th[r];
        al[si] = *(const short8*)&tlo[r];
      }
#pragma unroll
      for (int oj = 0; oj < 2; ++oj) {
        int r = (wv * 32 + oj * 16 + (lane & 15)) * 72 + ko;
        bh[oj] = *(const short8*)&ohh[r];
        bl[oj] = *(const short8*)&olo[r];
      }
#pragma unroll
      for (int si = 0; si < 4; ++si)
#pragma unroll
        for (int oj = 0; oj < 2; ++oj) {
          acc[si][oj] = __builtin_amdgcn_mfma_f32_16x16x32_bf16(
              ah[si], bh[oj], acc[si][oj], 0, 0, 0);
          acc[si][oj] = __builtin_amdgcn_mfma_f32_16x16x32_bf16(
              ah[si], bl[oj], acc[si][oj], 0, 0, 0);
          acc[si][oj] = __builtin_amdgcn_mfma_f32_16x16x32_bf16(
              al[si], bh[oj], acc[si][oj], 0, 0, 0);
        }
    }
  }
#undef K3_PF
  float* g = ws + OFF_G;
#pragma unroll
  for (int oj = 0; oj < 2; ++oj) {
    int o = o_blk + wv * 32 + oj * 16 + (lane & 15);
    float sc = cst[256 + o], bi = cst[512 + o];
#pragma unroll
    for (int si = 0; si < 4; ++si) {
      int sq = s0 + si * 16 + ((lane >> 4) << 2);
      float4 q;
      q.x = fmaxf(sc * acc[si][oj][0] + bi, 0.f);
      q.y = fmaxf(sc * acc[si][oj][1] + bi, 0.f);
      q.z = fmaxf(sc * acc[si][oj][2] + bi, 0.f);
      q.w = fmaxf(sc * acc[si][oj][3] + bi, 0.f);
      *(float4*)&g[((size_t)b * IS_ + o) * S_ + sq] = q;
    }
  }
}

// --------- k4a: y=relu(bn(W1@g)); ys=bn(W2@y); gate=sigmoid -> ws[GATE]
// grid (32 s-tiles, 8 b), 512 threads (8 waves). W1 staged in LDS once;
// inner loop is pure LDS (W1 reads wave-uniform -> broadcast).
__global__ __launch_bounds__(512) void k4a_gate(
    const float* __restrict__ W1, const float* __restrict__ W2,
    float* __restrict__ ws) {
  __shared__ float lds_g[128 * 65];    // 33.3 KB
  __shared__ float lds_w[32 * 260];    // 33.3 KB
  __shared__ float lds_y[32 * 65];     // 8.3 KB
  const int tid = threadIdx.x;
  const int s0  = blockIdx.x * 64;
  const int b   = blockIdx.y;
  const int s   = tid & 63;
  const int og  = tid >> 6;            // 8 groups x 4 y-rows
  const float* cst  = ws + OFF_CONST;
  const float* gsrc = ws + OFF_G + (size_t)b * IS_ * S_;

  // stage W1 [32][256] -> lds_w pitch 260 (one-time, 4 float4/thread)
#pragma unroll
  for (int j = 0; j < 4; ++j) {
    int f = tid + j * 512;             // 0..2047 float4 slots (32 rows x 64)
    int row = f >> 6, c4 = f & 63;
    *(float4*)&lds_w[row * 260 + c4 * 4] =
        *(const float4*)&W1[(size_t)row * IS_ + c4 * 4];
  }
  float acc[4] = {};

  for (int half = 0; half < 2; ++half) {
    __syncthreads();
#pragma unroll
    for (int j = 0; j < 16; ++j) {
      int idx = tid + j * 512;         // 8192 = 128 rows x 64
      lds_g[(idx >> 6) * 65 + (idx & 63)] =
          gsrc[(size_t)(half * 128 + (idx >> 6)) * S_ + s0 + (idx & 63)];
    }
    __syncthreads();
#pragma unroll
    for (int c4 = 0; c4 < 32; ++c4) {
      float g0 = lds_g[(c4 * 4 + 0) * 65 + s];
      float g1 = lds_g[(c4 * 4 + 1) * 65 + s];
      float g2 = lds_g[(c4 * 4 + 2) * 65 + s];
      float g3 = lds_g[(c4 * 4 + 3) * 65 + s];
#pragma unroll
      for (int j = 0; j < 4; ++j) {
        const float4 w = *(const float4*)&lds_w[(og * 4 + j) * 260 +
                                                half * 128 + c4 * 4];
        acc[j] += g0 * w.x + g1 * w.y + g2 * w.z + g3 * w.w;
      }
    }
  }
#pragma unroll
  for (int j = 0; j < 4; ++j) {
    int o = og * 4 + j;
    float v = cst[768 + o] * acc[j] + cst[800 + o];
    lds_y[o * 65 + s] = v > 0.f ? v : 0.f;
  }
  __syncthreads();
  if (tid < 64) {
    float sum = 0.f;
#pragma unroll
    for (int c = 0; c < 32; ++c) sum += W2[c] * lds_y[c * 65 + tid];
    float ys = cst[832] * sum + cst[833];
    ws[OFF_GATE + (size_t)b * S_ + s0 + tid] = 1.f / (1.f + expf(-ys));
  }
}

// --------------------------- k4b: out = x * gate  (pure stream, float4)
__global__ __launch_bounds__(256) void k4b_mul(
    const float* __restrict__ x, const float* __restrict__ ws,
    float* __restrict__ out) {
  const float* gate = ws + OFF_GATE;
  size_t i0 = (size_t)blockIdx.x * 256 + threadIdx.x;
  for (size_t f = i0; f < 2097152; f += 524288) {  // 8*512*2048/4 float4s
    size_t elem = f * 4;
    int b = (int)(elem >> 20);          // / (512*2048)
    int s = (int)(elem & 2047);
    float4 xv = *(const float4*)&x[elem];
    float4 gv = *(const float4*)&gate[(size_t)b * S_ + s];
    float4 ov;
    ov.x = xv.x * gv.x; ov.y = xv.y * gv.y;
    ov.z = xv.z * gv.z; ov.w = xv.w * gv.w;
    *(float4*)&out[elem] = ov;
  }
}

// ---------------------------------------------------------------------------
extern "C" void kernel_launch(void* const* d_in, const int* in_sizes, int n_in,
                              void* d_out, int out_size, void* d_ws, size_t ws_size,
                              hipStream_t stream) {
  const float* x   = (const float*)d_in[0];
  const float* Wt  = (const float*)d_in[1];
  const float* tg  = (const float*)d_in[2];
  const float* tb  = (const float*)d_in[3];
  const float* tm  = (const float*)d_in[4];
  const float* tv  = (const float*)d_in[5];
  const float* Wp  = (const float*)d_in[6];
  const float* pg  = (const float*)d_in[7];
  const float* pb  = (const float*)d_in[8];
  const float* pm  = (const float*)d_in[9];
  const float* pv  = (const float*)d_in[10];
  const float* Wgg = (const float*)d_in[11];
  const float* ggg = (const float*)d_in[12];
  const float* ggb = (const float*)d_in[13];
  const float* ggm = (const float*)d_in[14];
  const float* ggv = (const float*)d_in[15];
  const float* W1  = (const float*)d_in[16];
  const float* w1g = (const float*)d_in[17];
  const float* w1b = (const float*)d_in[18];
  const float* w1m = (const float*)d_in[19];
  const float* w1v = (const float*)d_in[20];
  const float* W2  = (const float*)d_in[21];
  const float* w2g = (const float*)d_in[22];
  const float* w2b = (const float*)d_in[23];
  const float* w2m = (const float*)d_in[24];
  const float* w2v = (const float*)d_in[25];
  float* ws  = (float*)d_ws;
  float* out = (float*)d_out;

  k0_consts<<<1, 256, 0, stream>>>(tg, tb, tm, tv, pg, pb, pm, pv,
                                   ggg, ggb, ggm, ggv, w1g, w1b, w1m, w1v,
                                   w2g, w2b, w2m, w2v, ws + OFF_CONST);
  k1_mfma<<<dim3(32, 8), 256, 0, stream>>>(
      x, Wt, Wp, ws + OFF_CONST, ws + OFF_THT, ws + OFF_PHT);
  k2_mfma<<<dim3(8, 2, 16), 256, 0, stream>>>(Wgg, ws, ws + OFF_AP);
  k2b_reduce<<<256, 256, 0, stream>>>(ws);
  k3_mfma<<<dim3(32, 2, 8), 256, 0, stream>>>(ws);
  k4a_gate<<<dim3(32, 8), 512, 0, stream>>>(W1, W2, ws);
  k4b_mul<<<2048, 256, 0, stream>>>(x, ws, out);
}